// Round 13
// baseline (168.782 us; speedup 1.0000x reference)
//
#include <hip/hip_runtime.h>
#include <hip/hip_bf16.h>

// SPQR dequant-GEMV via MFMA: y = x @ Wd^T + CSR, M=N=8192, B=10, beta=16x16.
// R13: ABLATION ROUND. Real kernels = R11 (best-known-correct). Appended
//      diagnostic probes (run AFTER reduce; write only to d_ws):
//        probe_tiled  = spqr_mfma's exact W access pattern, zero compute
//        probe_linear = ideal contiguous stream
//      Read their per-dispatch dur/FETCH from rocprof to locate the limiter.

constexpr int M_DIM = 8192;
constexpr int N_DIM = 8192;
constexpr int TN    = 512;              // N/16 scale groups per row
constexpr int BQ    = 10;               // batch (b*l)
constexpr int KSPLIT = 16;
constexpr int KRANGE = N_DIM / KSPLIT;  // 512
constexpr int KITERS = KRANGE / 32;     // 16 MFMA k-steps per wave
constexpr int RPB    = 64;              // rows per block (4 waves x 16)
constexpr int GPB    = KRANGE / 16;     // 32 scale groups per block k-range
constexpr int DEPTH  = 6;               // prefetch pairs in flight

typedef float  f32x4  __attribute__((ext_vector_type(4)));
typedef int    i32x4  __attribute__((ext_vector_type(4)));
typedef short  bf16x8 __attribute__((ext_vector_type(8)));

__device__ inline int pkbf(float a, float b) {     // -> v_cvt_pk_bf16_f32
    __hip_bfloat162 h = __float22bfloat162_rn(float2{a, b});
    int r;
    __builtin_memcpy(&r, &h, 4);
    return r;
}

__global__ __launch_bounds__(256, 4)
void spqr_mfma(const float* __restrict__ x,
               const int*   __restrict__ W,
               const int*   __restrict__ Ws,
               const int*   __restrict__ Wz,
               const float* __restrict__ Wss,
               const float* __restrict__ Wsz,
               const float* __restrict__ Wzs,
               const float* __restrict__ Wzz,
               const int*   __restrict__ row_offsets,
               const int*   __restrict__ col_ids,
               const float* __restrict__ values,
               float*       __restrict__ pws)
{
    const int t   = threadIdx.x;
    const int m0b = blockIdx.x * RPB;
    const int ks  = blockIdx.y;

    // ---- 17th slice: CSR outliers -> pws[KSPLIT] ----
    if (ks == KSPLIT) {
        const int r8 = t >> 5;              // 0..7
        const int j  = t & 31;
        float* pb = pws + (size_t)KSPLIT * (BQ * N_DIM);
        for (int rr = r8; rr < RPB; rr += 8) {
            const int m = m0b + rr;
            const int base = row_offsets[m];
            const int cnt  = row_offsets[m + 1] - base;
            float c[BQ];
            #pragma unroll
            for (int b = 0; b < BQ; ++b) c[b] = 0.f;
            for (int jj = j; jj < cnt; jj += 32) {
                const int   col = col_ids[base + jj];
                const float v   = values[base + jj];
                #pragma unroll
                for (int b = 0; b < BQ; ++b)
                    c[b] = fmaf(v, x[b * N_DIM + col], c[b]);
            }
            #pragma unroll
            for (int b = 0; b < BQ; ++b) {
                float v = c[b];
                for (int off = 16; off > 0; off >>= 1)
                    v += __shfl_xor(v, off, 32);
                c[b] = v;
            }
            if (j == 0) {
                #pragma unroll
                for (int b = 0; b < BQ; ++b)
                    pb[(size_t)b * N_DIM + m] = c[b];
            }
        }
        return;
    }

    __shared__ int ldsA[KITERS * 64 * 4];          // 16KB: bf16 A-frags
    __shared__ int ldsSZ[RPB * 33];                // 8.25KB: packed (s, -z*s) bf16x2

    const int k0 = ks * KRANGE;
    const int g0 = k0 >> 4;

    // ---- stage A-fragments: lane l of k-iter kk holds x[b=l&15][k0+kk*32+(l>>4)*8 ..+7]
    for (int idx = t; idx < KITERS * 64; idx += 256) {
        const int kk = idx >> 6, l = idx & 63;
        const int b = l & 15, koff = (kk << 5) + ((l >> 4) << 3);
        int out[4] = {0, 0, 0, 0};
        if (b < BQ) {
            const float* xp = x + b * N_DIM + k0 + koff;
            f32x4 lo = *reinterpret_cast<const f32x4*>(xp);
            f32x4 hi = *reinterpret_cast<const f32x4*>(xp + 4);
            out[0] = pkbf(lo.x, lo.y);
            out[1] = pkbf(lo.z, lo.w);
            out[2] = pkbf(hi.x, hi.y);
            out[3] = pkbf(hi.z, hi.w);
        }
        *reinterpret_cast<i32x4*>(&ldsA[idx * 4]) = *reinterpret_cast<i32x4*>(out);
    }

    // ---- stage packed first-order (s, -z*s) as bf16 pair
    for (int idx = t; idx < RPB * GPB; idx += 256) {
        const int rl = idx >> 5;                   // local row 0..63
        const int gl = idx & 31;                   // local group 0..31
        const int m = m0b + rl, g = g0 + gl;
        const int tix = (m >> 4) * TN + g;
        const float s = ((float)Ws[m * TN + g] - Wsz[tix]) * Wss[tix];
        const float z = ((float)Wz[m * TN + g] - Wzz[tix]) * Wzs[tix];
        ldsSZ[rl * 33 + gl] = pkbf(s, -z * s);
    }
    __syncthreads();

    // ---- main loop: stream W codes (6-deep pair prefetch), dequant, MFMA ----
    const int wv = t >> 6, l = t & 63;
    const int lrow = l & 15;                       // tile row
    const int lk   = l >> 4;                       // k-sub 0..3
    const int m0   = m0b + (wv << 4);
    const int* wp  = W + (size_t)(m0 + lrow) * N_DIM + k0 + (lk << 3);
    const int szrow = (wv << 4) + lrow;
    const int szk   = lk >> 1;

    f32x4 acc = {0.f, 0.f, 0.f, 0.f};
    i32x4 cbufL[DEPTH], cbufH[DEPTH];

    #pragma unroll
    for (int p = 0; p < DEPTH; ++p) {
        cbufL[p] = *reinterpret_cast<const i32x4*>(wp + p * 32);
        cbufH[p] = *reinterpret_cast<const i32x4*>(wp + p * 32 + 4);
    }

    #pragma unroll
    for (int kk = 0; kk < KITERS; ++kk) {
        const i32x4 cl = cbufL[kk % DEPTH], ch = cbufH[kk % DEPTH];
        if (kk + DEPTH < KITERS) {
            cbufL[kk % DEPTH] =
                *reinterpret_cast<const i32x4*>(wp + (kk + DEPTH) * 32);
            cbufH[kk % DEPTH] =
                *reinterpret_cast<const i32x4*>(wp + (kk + DEPTH) * 32 + 4);
        }
        const i32x4 a4 = *reinterpret_cast<const i32x4*>(&ldsA[(kk * 64 + l) * 4]);
        const int spk = ldsSZ[szrow * 33 + kk * 2 + szk];
        const float s   = __uint_as_float((unsigned)spk << 16);
        const float nzs = __uint_as_float((unsigned)spk & 0xffff0000u);
        int bw[4];
        bw[0] = pkbf(fmaf((float)cl.x, s, nzs), fmaf((float)cl.y, s, nzs));
        bw[1] = pkbf(fmaf((float)cl.z, s, nzs), fmaf((float)cl.w, s, nzs));
        bw[2] = pkbf(fmaf((float)ch.x, s, nzs), fmaf((float)ch.y, s, nzs));
        bw[3] = pkbf(fmaf((float)ch.z, s, nzs), fmaf((float)ch.w, s, nzs));
        const bf16x8 af = __builtin_bit_cast(bf16x8, a4);
        i32x4 bwv = *reinterpret_cast<i32x4*>(bw);
        const bf16x8 bf = __builtin_bit_cast(bf16x8, bwv);
        acc = __builtin_amdgcn_mfma_f32_16x16x32_bf16(af, bf, acc, 0, 0, 0);
    }

    // ---- store partials: C[row=b=(l>>4)*4+j][col=lrow] -> pws[ks][b][m0+lrow]
    float* pb = pws + (size_t)ks * (BQ * N_DIM) + (m0 + lrow);
    #pragma unroll
    for (int j = 0; j < 4; ++j) {
        const int b = (lk << 2) + j;
        if (b < BQ) pb[(size_t)b * N_DIM] = acc[j];
    }
}

__global__ __launch_bounds__(256, 4)
void spqr_reduce(const float* __restrict__ pws,
                 float*       __restrict__ y)
{
    const int gid = blockIdx.x * 256 + threadIdx.x;       // 0 .. 10*8192-1
    if (gid >= BQ * M_DIM) return;
    const int b = gid / M_DIM;
    const int m = gid - b * M_DIM;
    const float* pp = pws + (size_t)b * N_DIM + m;
    float v = 0.f;
    #pragma unroll
    for (int ksp = 0; ksp < KSPLIT + 1; ++ksp)
        v += pp[(size_t)ksp * (BQ * N_DIM)];
    y[(size_t)b * M_DIM + m] = v;
}

// ---- DIAGNOSTIC PROBES (write only to d_ws, run after reduce) ----

__global__ __launch_bounds__(256, 4)
void probe_tiled(const int* __restrict__ W, int* __restrict__ sink)
{
    // exact spqr_mfma W pattern: grid (128,16), wave = 16-row x 512-col tile
    const int t   = threadIdx.x;
    const int m0b = blockIdx.x * RPB;
    const int k0  = blockIdx.y * KRANGE;
    const int wv = t >> 6, l = t & 63;
    const int lrow = l & 15, lk = l >> 4;
    const int m0 = m0b + (wv << 4);
    const int* wp = W + (size_t)(m0 + lrow) * N_DIM + k0 + (lk << 3);
    i32x4 s = {0, 0, 0, 0};
    #pragma unroll
    for (int kk = 0; kk < KITERS; ++kk) {
        const i32x4 a = *reinterpret_cast<const i32x4*>(wp + kk * 32);
        const i32x4 b = *reinterpret_cast<const i32x4*>(wp + kk * 32 + 4);
        s ^= a ^ b;
    }
    sink[(blockIdx.y * gridDim.x + blockIdx.x) * 256 + t] = s.x ^ s.y ^ s.z ^ s.w;
}

__global__ __launch_bounds__(256, 4)
void probe_linear(const int* __restrict__ W, int* __restrict__ sink)
{
    // ideal stream: block = contiguous 128KB slab, lane-contiguous dwordx4
    const size_t base = (size_t)blockIdx.x * 32768 + (size_t)threadIdx.x * 4;
    i32x4 s = {0, 0, 0, 0};
    #pragma unroll
    for (int i = 0; i < 32; ++i)
        s ^= *reinterpret_cast<const i32x4*>(W + base + (size_t)i * 1024);
    sink[blockIdx.x * 256 + threadIdx.x] = s.x ^ s.y ^ s.z ^ s.w;
}

extern "C" void kernel_launch(void* const* d_in, const int* in_sizes, int n_in,
                              void* d_out, int out_size, void* d_ws, size_t ws_size,
                              hipStream_t stream)
{
    const float* x    = (const float*)d_in[0];
    const int*   W    = (const int*)  d_in[1];
    const int*   Ws   = (const int*)  d_in[2];
    const int*   Wz   = (const int*)  d_in[3];
    const float* Wss  = (const float*)d_in[4];
    const float* Wsz  = (const float*)d_in[5];
    const float* Wzs  = (const float*)d_in[6];
    const float* Wzz  = (const float*)d_in[7];
    const int*   roff = (const int*)  d_in[8];
    const int*   cids = (const int*)  d_in[9];
    const float* vals = (const float*)d_in[10];
    float* yout = (float*)d_out;
    float* pws  = (float*)d_ws;                   // 17 x 10 x 8192 f32 = 5.57 MB

    dim3 grid1(M_DIM / RPB, KSPLIT + 1);          // 128 x 17 blocks
    spqr_mfma<<<grid1, dim3(256), 0, stream>>>(x, W, Ws, Wz, Wss, Wsz, Wzs, Wzz,
                                               roff, cids, vals, pws);

    dim3 grid2((BQ * M_DIM + 255) / 256);         // 320 blocks
    spqr_reduce<<<grid2, dim3(256), 0, stream>>>(pws, yout);

    // probes reuse pws as sink AFTER reduce has consumed it (same stream)
    int* sink = (int*)d_ws;
    probe_tiled<<<dim3(M_DIM / RPB, KSPLIT), dim3(256), 0, stream>>>(W, sink);
    probe_linear<<<dim3(2048), dim3(256), 0, stream>>>(W, sink);
}

// Round 14
// 107.090 us; speedup vs baseline: 1.5761x; 1.5761x over previous
//
#include <hip/hip_runtime.h>
#include <hip/hip_bf16.h>

// SPQR dequant-GEMV via MFMA: y = x @ Wd^T + CSR, M=N=8192, B=10, beta=16x16.
// R14: W staged via global_load_lds (fire-and-forget: no dest regs, compiler
//      can't sink it), wave-private double-buffered 16x32-code tiles, counted
//      vmcnt(2) pacing, ZERO barriers in the main loop. Source-side XOR
//      swizzle (inverse on global addr, forward on LDS read) kills the
//      16-way bank conflict. LDS exactly 40KB -> 4 blocks/CU.

constexpr int M_DIM = 8192;
constexpr int N_DIM = 8192;
constexpr int TN    = 512;              // N/16 scale groups per row
constexpr int BQ    = 10;               // batch (b*l)
constexpr int KSPLIT = 16;
constexpr int KRANGE = N_DIM / KSPLIT;  // 512
constexpr int KITERS = KRANGE / 32;     // 16 MFMA k-steps per wave
constexpr int RPB    = 64;              // rows per block (4 waves x 16)
constexpr int GPB    = KRANGE / 16;     // 32 scale groups per block k-range

typedef float  f32x4  __attribute__((ext_vector_type(4)));
typedef int    i32x4  __attribute__((ext_vector_type(4)));
typedef short  bf16x8 __attribute__((ext_vector_type(8)));

#define AS1C(p) ((const __attribute__((address_space(1))) void*)(p))
#define AS3(p)  ((__attribute__((address_space(3))) void*)(p))

__device__ inline int pkbf(float a, float b) {     // -> v_cvt_pk_bf16_f32
    __hip_bfloat162 h = __float22bfloat162_rn(float2{a, b});
    int r;
    __builtin_memcpy(&r, &h, 4);
    return r;
}

template<int N>
__device__ __forceinline__ void wait_vm() {
    asm volatile("s_waitcnt vmcnt(%0)" :: "n"(N));
    __builtin_amdgcn_sched_barrier(0);
}

__global__ __launch_bounds__(256, 4)
void spqr_mfma(const float* __restrict__ x,
               const int*   __restrict__ W,
               const int*   __restrict__ Ws,
               const int*   __restrict__ Wz,
               const float* __restrict__ Wss,
               const float* __restrict__ Wsz,
               const float* __restrict__ Wzs,
               const float* __restrict__ Wzz,
               const int*   __restrict__ row_offsets,
               const int*   __restrict__ col_ids,
               const float* __restrict__ values,
               float*       __restrict__ pws)
{
    const int t   = threadIdx.x;
    const int m0b = blockIdx.x * RPB;
    const int ks  = blockIdx.y;

    // ---- 17th slice: CSR outliers -> pws[KSPLIT] ----
    if (ks == KSPLIT) {
        const int r8 = t >> 5;              // 0..7
        const int j  = t & 31;
        float* pb = pws + (size_t)KSPLIT * (BQ * N_DIM);
        for (int rr = r8; rr < RPB; rr += 8) {
            const int m = m0b + rr;
            const int base = row_offsets[m];
            const int cnt  = row_offsets[m + 1] - base;
            float c[BQ];
            #pragma unroll
            for (int b = 0; b < BQ; ++b) c[b] = 0.f;
            for (int jj = j; jj < cnt; jj += 32) {
                const int   col = col_ids[base + jj];
                const float v   = values[base + jj];
                #pragma unroll
                for (int b = 0; b < BQ; ++b)
                    c[b] = fmaf(v, x[b * N_DIM + col], c[b]);
            }
            #pragma unroll
            for (int b = 0; b < BQ; ++b) {
                float v = c[b];
                for (int off = 16; off > 0; off >>= 1)
                    v += __shfl_xor(v, off, 32);
                c[b] = v;
            }
            if (j == 0) {
                #pragma unroll
                for (int b = 0; b < BQ; ++b)
                    pb[(size_t)b * N_DIM + m] = c[b];
            }
        }
        return;
    }

    __shared__ int ldsA[KITERS * 64 * 4];   // 16KB: bf16 A-frags per k-iter/lane
    __shared__ int ldsSZ[RPB * 32];         // 8KB: packed (s,-z*s), XOR-swizzled
    __shared__ int stg[2 * 4 * 512];        // 16KB: W-code tiles, dbuf x wave x 2KB

    const int k0 = ks * KRANGE;
    const int g0 = k0 >> 4;

    const int wv = t >> 6, l = t & 63;
    const int lrow = l & 15;                // tile row (W row offset / C col)
    const int lk   = l >> 4;                // k-sub 0..3
    const int m0   = m0b + (wv << 4);

    // per-lane swizzled global staging addresses (involution: chunk ^= row&7)
    const int sr0 = l >> 3;                 // staged row (instr0: rows 0..7)
    const int sc0 = (l & 7) ^ (sr0 & 7);    // inverse-swizzled 16B chunk
    const int sr1 = sr0 + 8;                // instr1: rows 8..15
    const int sc1 = (l & 7) ^ (sr1 & 7);
    const int* gs0 = W + (size_t)(m0 + sr0) * N_DIM + k0 + sc0 * 4;
    const int* gs1 = W + (size_t)(m0 + sr1) * N_DIM + k0 + sc1 * 4;
    int* stw = &stg[wv * 512];              // this wave's tile (within buffer 0)

#define STAGE(kk) do {                                                        \
    int* d_ = stw + ((kk) & 1) * 2048;                                        \
    __builtin_amdgcn_global_load_lds(AS1C(gs0 + (kk) * 32), AS3(d_),       16, 0, 0); \
    __builtin_amdgcn_global_load_lds(AS1C(gs1 + (kk) * 32), AS3(d_ + 256), 16, 0, 0); \
} while (0)

    STAGE(0);   // in flight under the staging loops below; drained by barrier

    // ---- stage A-fragments: lane l of k-iter kk holds x[b=l&15][k0+kk*32+(l>>4)*8 ..+7]
    for (int idx = t; idx < KITERS * 64; idx += 256) {
        const int kk = idx >> 6, ll = idx & 63;
        const int b = ll & 15, koff = (kk << 5) + ((ll >> 4) << 3);
        int out[4] = {0, 0, 0, 0};
        if (b < BQ) {
            const float* xp = x + b * N_DIM + k0 + koff;
            f32x4 lo = *reinterpret_cast<const f32x4*>(xp);
            f32x4 hi = *reinterpret_cast<const f32x4*>(xp + 4);
            out[0] = pkbf(lo.x, lo.y);
            out[1] = pkbf(lo.z, lo.w);
            out[2] = pkbf(hi.x, hi.y);
            out[3] = pkbf(hi.z, hi.w);
        }
        *reinterpret_cast<i32x4*>(&ldsA[idx * 4]) = *reinterpret_cast<i32x4*>(out);
    }

    // ---- stage packed first-order (s, -z*s), XOR-swizzled (row-spread banks)
    for (int idx = t; idx < RPB * GPB; idx += 256) {
        const int rl = idx >> 5;            // local row 0..63
        const int gl = idx & 31;            // local group 0..31
        const int m = m0b + rl, g = g0 + gl;
        const int tix = (m >> 4) * TN + g;
        const float s = ((float)Ws[m * TN + g] - Wsz[tix]) * Wss[tix];
        const float z = ((float)Wz[m * TN + g] - Wzz[tix]) * Wzs[tix];
        ldsSZ[rl * 32 + (gl ^ (rl & 31))] = pkbf(s, -z * s);
    }
    __syncthreads();    // publishes ldsA/ldsSZ; drains vmcnt (STAGE(0) done)

    // ---- main loop: wave-private staged tiles, NO barriers ----
    const int szrow = (wv << 4) + lrow;
    const int szk   = lk >> 1;
    // swizzled read offset within tile (ints): row*32 + (chunk ^ (row&7))*4
    const int roff  = lrow * 32 + (((lk * 2) ^ (lrow & 7)) * 4);

    f32x4 acc = {0.f, 0.f, 0.f, 0.f};

    #pragma unroll
    for (int kk = 0; kk < KITERS; ++kk) {
        if (kk + 1 < KITERS) STAGE(kk + 1);
        // a4 / spk reads are independent of the staged tile: above the fence
        const i32x4 a4 = *reinterpret_cast<const i32x4*>(&ldsA[(kk * 64 + l) * 4]);
        const int gi  = kk * 2 + szk;
        const int spk = ldsSZ[szrow * 32 + (gi ^ (szrow & 31))];
        // wait for tile kk (keep kk+1's 2 loads in flight); tail drains to 0
        if (kk + 1 < KITERS) wait_vm<2>(); else wait_vm<0>();
        const int* tile = stw + (kk & 1) * 2048;
        const i32x4 cl = *reinterpret_cast<const i32x4*>(&tile[roff]);
        const i32x4 ch = *reinterpret_cast<const i32x4*>(&tile[roff ^ 4]);
        const float s   = __uint_as_float((unsigned)spk << 16);
        const float nzs = __uint_as_float((unsigned)spk & 0xffff0000u);
        int bw[4];
        bw[0] = pkbf(fmaf((float)cl.x, s, nzs), fmaf((float)cl.y, s, nzs));
        bw[1] = pkbf(fmaf((float)cl.z, s, nzs), fmaf((float)cl.w, s, nzs));
        bw[2] = pkbf(fmaf((float)ch.x, s, nzs), fmaf((float)ch.y, s, nzs));
        bw[3] = pkbf(fmaf((float)ch.z, s, nzs), fmaf((float)ch.w, s, nzs));
        const bf16x8 af = __builtin_bit_cast(bf16x8, a4);
        i32x4 bwv = *reinterpret_cast<i32x4*>(bw);
        const bf16x8 bf = __builtin_bit_cast(bf16x8, bwv);
        acc = __builtin_amdgcn_mfma_f32_16x16x32_bf16(af, bf, acc, 0, 0, 0);
    }
#undef STAGE

    // ---- store partials: C[row=b=(l>>4)*4+j][col=lrow] -> pws[ks][b][m0+lrow]
    float* pb = pws + (size_t)ks * (BQ * N_DIM) + (m0 + lrow);
    #pragma unroll
    for (int j = 0; j < 4; ++j) {
        const int b = (lk << 2) + j;
        if (b < BQ) pb[(size_t)b * N_DIM] = acc[j];
    }
}

__global__ __launch_bounds__(256, 4)
void spqr_reduce(const float* __restrict__ pws,
                 float*       __restrict__ y)
{
    // one thread per (b, m) output: sum 17 slices
    const int gid = blockIdx.x * 256 + threadIdx.x;       // 0 .. 10*8192-1
    if (gid >= BQ * M_DIM) return;
    const int b = gid / M_DIM;
    const int m = gid - b * M_DIM;
    const float* pp = pws + (size_t)b * N_DIM + m;
    float v = 0.f;
    #pragma unroll
    for (int ksp = 0; ksp < KSPLIT + 1; ++ksp)
        v += pp[(size_t)ksp * (BQ * N_DIM)];
    y[(size_t)b * M_DIM + m] = v;
}

extern "C" void kernel_launch(void* const* d_in, const int* in_sizes, int n_in,
                              void* d_out, int out_size, void* d_ws, size_t ws_size,
                              hipStream_t stream)
{
    const float* x    = (const float*)d_in[0];
    const int*   W    = (const int*)  d_in[1];
    const int*   Ws   = (const int*)  d_in[2];
    const int*   Wz   = (const int*)  d_in[3];
    const float* Wss  = (const float*)d_in[4];
    const float* Wsz  = (const float*)d_in[5];
    const float* Wzs  = (const float*)d_in[6];
    const float* Wzz  = (const float*)d_in[7];
    const int*   roff = (const int*)  d_in[8];
    const int*   cids = (const int*)  d_in[9];
    const float* vals = (const float*)d_in[10];
    float* yout = (float*)d_out;
    float* pws  = (float*)d_ws;                   // 17 x 10 x 8192 f32 = 5.57 MB

    dim3 grid1(M_DIM / RPB, KSPLIT + 1);          // 128 x 17 blocks
    spqr_mfma<<<grid1, dim3(256), 0, stream>>>(x, W, Ws, Wz, Wss, Wsz, Wzs, Wzz,
                                               roff, cids, vals, pws);

    dim3 grid2((BQ * M_DIM + 255) / 256);         // 320 blocks
    spqr_reduce<<<grid2, dim3(256), 0, stream>>>(pws, yout);
}

// Round 15
// 90.013 us; speedup vs baseline: 1.8751x; 1.1897x over previous
//
#include <hip/hip_runtime.h>
#include <hip/hip_bf16.h>

// SPQR dequant-GEMV via MFMA: y = x @ Wd^T + CSR, M=N=8192, B=10, beta=16x16.
// R15: probe-style batched issue. 4 super-chunks of 4 tiles; asm-volatile
//      global_load_dwordx4 with immediate offsets (order pinned), named
//      double-buffered i32x4 regs (peak 64 VGPR of buffers), counted
//      vmcnt(8)+sched_barrier between phases. 16KB/wave in flight through
//      every consume phase. Rest identical to R11.

constexpr int M_DIM = 8192;
constexpr int N_DIM = 8192;
constexpr int TN    = 512;              // N/16 scale groups per row
constexpr int BQ    = 10;               // batch (b*l)
constexpr int KSPLIT = 16;
constexpr int KRANGE = N_DIM / KSPLIT;  // 512
constexpr int KITERS = KRANGE / 32;     // 16 MFMA k-steps per wave
constexpr int RPB    = 64;              // rows per block (4 waves x 16)
constexpr int GPB    = KRANGE / 16;     // 32 scale groups per block k-range

typedef float  f32x4  __attribute__((ext_vector_type(4)));
typedef int    i32x4  __attribute__((ext_vector_type(4)));
typedef short  bf16x8 __attribute__((ext_vector_type(8)));

__device__ inline int pkbf(float a, float b) {     // -> v_cvt_pk_bf16_f32
    __hip_bfloat162 h = __float22bfloat162_rn(float2{a, b});
    int r;
    __builtin_memcpy(&r, &h, 4);
    return r;
}

__global__ __launch_bounds__(256, 4)
void spqr_mfma(const float* __restrict__ x,
               const int*   __restrict__ W,
               const int*   __restrict__ Ws,
               const int*   __restrict__ Wz,
               const float* __restrict__ Wss,
               const float* __restrict__ Wsz,
               const float* __restrict__ Wzs,
               const float* __restrict__ Wzz,
               const int*   __restrict__ row_offsets,
               const int*   __restrict__ col_ids,
               const float* __restrict__ values,
               float*       __restrict__ pws)
{
    const int t   = threadIdx.x;
    const int m0b = blockIdx.x * RPB;
    const int ks  = blockIdx.y;

    // ---- 17th slice: CSR outliers -> pws[KSPLIT] ----
    if (ks == KSPLIT) {
        const int r8 = t >> 5;              // 0..7
        const int j  = t & 31;
        float* pb = pws + (size_t)KSPLIT * (BQ * N_DIM);
        for (int rr = r8; rr < RPB; rr += 8) {
            const int m = m0b + rr;
            const int base = row_offsets[m];
            const int cnt  = row_offsets[m + 1] - base;
            float c[BQ];
            #pragma unroll
            for (int b = 0; b < BQ; ++b) c[b] = 0.f;
            for (int jj = j; jj < cnt; jj += 32) {
                const int   col = col_ids[base + jj];
                const float v   = values[base + jj];
                #pragma unroll
                for (int b = 0; b < BQ; ++b)
                    c[b] = fmaf(v, x[b * N_DIM + col], c[b]);
            }
            #pragma unroll
            for (int b = 0; b < BQ; ++b) {
                float v = c[b];
                for (int off = 16; off > 0; off >>= 1)
                    v += __shfl_xor(v, off, 32);
                c[b] = v;
            }
            if (j == 0) {
                #pragma unroll
                for (int b = 0; b < BQ; ++b)
                    pb[(size_t)b * N_DIM + m] = c[b];
            }
        }
        return;
    }

    __shared__ int ldsA[KITERS * 64 * 4];          // 16KB: bf16 A-frags
    __shared__ int ldsSZ[RPB * 33];                // 8.25KB: packed (s, -z*s) bf16x2

    const int k0 = ks * KRANGE;
    const int g0 = k0 >> 4;

    // ---- stage A-fragments: lane l of k-iter kk holds x[b=l&15][k0+kk*32+(l>>4)*8 ..+7]
    for (int idx = t; idx < KITERS * 64; idx += 256) {
        const int kk = idx >> 6, ll = idx & 63;
        const int b = ll & 15, koff = (kk << 5) + ((ll >> 4) << 3);
        int out[4] = {0, 0, 0, 0};
        if (b < BQ) {
            const float* xp = x + b * N_DIM + k0 + koff;
            f32x4 lo = *reinterpret_cast<const f32x4*>(xp);
            f32x4 hi = *reinterpret_cast<const f32x4*>(xp + 4);
            out[0] = pkbf(lo.x, lo.y);
            out[1] = pkbf(lo.z, lo.w);
            out[2] = pkbf(hi.x, hi.y);
            out[3] = pkbf(hi.z, hi.w);
        }
        *reinterpret_cast<i32x4*>(&ldsA[idx * 4]) = *reinterpret_cast<i32x4*>(out);
    }

    // ---- stage packed first-order (s, -z*s) as bf16 pair (padded, conflict-free)
    for (int idx = t; idx < RPB * GPB; idx += 256) {
        const int rl = idx >> 5;                   // local row 0..63
        const int gl = idx & 31;                   // local group 0..31
        const int m = m0b + rl, g = g0 + gl;
        const int tix = (m >> 4) * TN + g;
        const float s = ((float)Ws[m * TN + g] - Wsz[tix]) * Wss[tix];
        const float z = ((float)Wz[m * TN + g] - Wzz[tix]) * Wzs[tix];
        ldsSZ[rl * 33 + gl] = pkbf(s, -z * s);
    }
    __syncthreads();   // publishes LDS; drains vmcnt to 0 (clean count baseline)

    // ---- main: straight-line super-chunk schedule ----
    const int wv = t >> 6, l = t & 63;
    const int lrow = l & 15;                       // tile row
    const int lk   = l >> 4;                       // k-sub 0..3
    const int m0   = m0b + (wv << 4);
    const int* wp  = W + (size_t)(m0 + lrow) * N_DIM + k0 + (lk << 3);
    const int szrow = (wv << 4) + lrow;
    const int szk   = lk >> 1;

    f32x4 acc = {0.f, 0.f, 0.f, 0.f};
    i32x4 bL0, bL1, bL2, bL3, bH0, bH1, bH2, bH3;
    i32x4 cL0, cL1, cL2, cL3, cH0, cH1, cH2, cH3;

#define GL(dst, OFF) \
    asm volatile("global_load_dwordx4 %0, %1, off offset:%2" \
                 : "=v"(dst) : "v"(wp), "n"(OFF));

#define ISSUE(P, T0) \
    GL(P##L0, ((T0) + 0) * 128)  GL(P##H0, ((T0) + 0) * 128 + 16) \
    GL(P##L1, ((T0) + 1) * 128)  GL(P##H1, ((T0) + 1) * 128 + 16) \
    GL(P##L2, ((T0) + 2) * 128)  GL(P##H2, ((T0) + 2) * 128 + 16) \
    GL(P##L3, ((T0) + 3) * 128)  GL(P##H3, ((T0) + 3) * 128 + 16)

#define WAITSB(N) \
    asm volatile("s_waitcnt vmcnt(" #N ")" ::: "memory"); \
    __builtin_amdgcn_sched_barrier(0);

#define CONSUME(kk, CL, CH) do {                                              \
    const i32x4 a4 = *reinterpret_cast<const i32x4*>(&ldsA[((kk) * 64 + l) * 4]); \
    const int spk = ldsSZ[szrow * 33 + (kk) * 2 + szk];                       \
    const float s_   = __uint_as_float((unsigned)spk << 16);                  \
    const float nzs_ = __uint_as_float((unsigned)spk & 0xffff0000u);          \
    int bw[4];                                                                \
    bw[0] = pkbf(fmaf((float)CL.x, s_, nzs_), fmaf((float)CL.y, s_, nzs_));   \
    bw[1] = pkbf(fmaf((float)CL.z, s_, nzs_), fmaf((float)CL.w, s_, nzs_));   \
    bw[2] = pkbf(fmaf((float)CH.x, s_, nzs_), fmaf((float)CH.y, s_, nzs_));   \
    bw[3] = pkbf(fmaf((float)CH.z, s_, nzs_), fmaf((float)CH.w, s_, nzs_));   \
    const bf16x8 af = __builtin_bit_cast(bf16x8, a4);                         \
    i32x4 bwv = *reinterpret_cast<i32x4*>(bw);                                \
    const bf16x8 bfv = __builtin_bit_cast(bf16x8, bwv);                       \
    acc = __builtin_amdgcn_mfma_f32_16x16x32_bf16(af, bfv, acc, 0, 0, 0);     \
} while (0)

    ISSUE(b, 0)                     // tiles 0..3   (8 loads)
    ISSUE(c, 4)                     // tiles 4..7   (outstanding 16)
    WAITSB(8)                       // tiles 0..3 landed; 4..7 in flight
    CONSUME(0, bL0, bH0); CONSUME(1, bL1, bH1);
    CONSUME(2, bL2, bH2); CONSUME(3, bL3, bH3);
    ISSUE(b, 8)                     // tiles 8..11  (outstanding <=16)
    WAITSB(8)                       // tiles 4..7 landed; 8..11 in flight
    CONSUME(4, cL0, cH0); CONSUME(5, cL1, cH1);
    CONSUME(6, cL2, cH2); CONSUME(7, cL3, cH3);
    ISSUE(c, 12)                    // tiles 12..15
    WAITSB(8)                       // tiles 8..11 landed; 12..15 in flight
    CONSUME(8, bL0, bH0); CONSUME(9, bL1, bH1);
    CONSUME(10, bL2, bH2); CONSUME(11, bL3, bH3);
    WAITSB(0)                       // tail drain
    CONSUME(12, cL0, cH0); CONSUME(13, cL1, cH1);
    CONSUME(14, cL2, cH2); CONSUME(15, cL3, cH3);

#undef GL
#undef ISSUE
#undef WAITSB
#undef CONSUME

    // ---- store partials: C[row=b=(l>>4)*4+j][col=lrow] -> pws[ks][b][m0+lrow]
    float* pb = pws + (size_t)ks * (BQ * N_DIM) + (m0 + lrow);
    #pragma unroll
    for (int j = 0; j < 4; ++j) {
        const int b = (lk << 2) + j;
        if (b < BQ) pb[(size_t)b * N_DIM] = acc[j];
    }
}

__global__ __launch_bounds__(256, 4)
void spqr_reduce(const float* __restrict__ pws,
                 float*       __restrict__ y)
{
    // one thread per (b, m) output: sum 17 slices
    const int gid = blockIdx.x * 256 + threadIdx.x;       // 0 .. 10*8192-1
    if (gid >= BQ * M_DIM) return;
    const int b = gid / M_DIM;
    const int m = gid - b * M_DIM;
    const float* pp = pws + (size_t)b * N_DIM + m;
    float v = 0.f;
    #pragma unroll
    for (int ksp = 0; ksp < KSPLIT + 1; ++ksp)
        v += pp[(size_t)ksp * (BQ * N_DIM)];
    y[(size_t)b * M_DIM + m] = v;
}

extern "C" void kernel_launch(void* const* d_in, const int* in_sizes, int n_in,
                              void* d_out, int out_size, void* d_ws, size_t ws_size,
                              hipStream_t stream)
{
    const float* x    = (const float*)d_in[0];
    const int*   W    = (const int*)  d_in[1];
    const int*   Ws   = (const int*)  d_in[2];
    const int*   Wz   = (const int*)  d_in[3];
    const float* Wss  = (const float*)d_in[4];
    const float* Wsz  = (const float*)d_in[5];
    const float* Wzs  = (const float*)d_in[6];
    const float* Wzz  = (const float*)d_in[7];
    const int*   roff = (const int*)  d_in[8];
    const int*   cids = (const int*)  d_in[9];
    const float* vals = (const float*)d_in[10];
    float* yout = (float*)d_out;
    float* pws  = (float*)d_ws;                   // 17 x 10 x 8192 f32 = 5.57 MB

    dim3 grid1(M_DIM / RPB, KSPLIT + 1);          // 128 x 17 blocks
    spqr_mfma<<<grid1, dim3(256), 0, stream>>>(x, W, Ws, Wz, Wss, Wsz, Wzs, Wzz,
                                               roff, cids, vals, pws);

    dim3 grid2((BQ * M_DIM + 255) / 256);         // 320 blocks
    spqr_reduce<<<grid2, dim3(256), 0, stream>>>(pws, yout);
}